// Round 3
// baseline (325.004 us; speedup 1.0000x reference)
//
#include <hip/hip_runtime.h>
#include <hip/hip_bf16.h>
#include <stdint.h>

typedef __bf16 bf16_t;
typedef __bf16 bf16x4 __attribute__((ext_vector_type(4)));
typedef __bf16 bf16x8 __attribute__((ext_vector_type(8)));
typedef float  f32x4  __attribute__((ext_vector_type(4)));

#define AS1 __attribute__((address_space(1)))
#define AS3 __attribute__((address_space(3)))

// async global->LDS, 16B per lane; lds dest = wave-uniform base + lane*16
__device__ __forceinline__ void gld_lds16(const void* gp, void* lp) {
    __builtin_amdgcn_global_load_lds((const AS1 unsigned int*)gp,
                                     (AS3 unsigned int*)lp, 16, 0, 0);
}

__device__ __forceinline__ bf16_t bhi(float v) { return (bf16_t)v; }
__device__ __forceinline__ bf16_t blo(float v) {
    return (bf16_t)(v - (float)((bf16_t)v));
}

// ---------------------------------------------------------------------------
// Kernel 1: W fp32 -> bf16
// ---------------------------------------------------------------------------
__global__ __launch_bounds__(256) void wconv_kernel(const float* __restrict__ W,
                                                    bf16_t* __restrict__ Wb) {
    const int i = (blockIdx.x * 256 + threadIdx.x) * 4;
    const float4 f = *(const float4*)&W[i];
    bf16x4 v = { (bf16_t)f.x, (bf16_t)f.y, (bf16_t)f.z, (bf16_t)f.w };
    *(bf16x4*)&Wb[i] = v;
}

// ---------------------------------------------------------------------------
// Kernel 2: attention per (b,h).  L=64, E=128.  fp32 inputs, bf16 X out.
// Scores computed EXACTLY as (Qh+Ql)(Kh+Kl) via 4 Gray-code MFMA passes:
//   (h,h) -> (h,l) -> (l,l) -> (l,h)   (one LDS slot restaged per pass)
// then fp32 softmax(0.1*S), PV in bf16 MFMA.
// writes X[(b*64+l)][h*128+d] bf16 (row stride 2048)
// ---------------------------------------------------------------------------
#define QK_LD 136   // 128 + 8 pad (keeps 16B align for ds_read_b128)
#define VT_LD 72    // 64 + 8 pad
#define SF_LD 65

__global__ __launch_bounds__(256) void attn_kernel(const float* __restrict__ Q,
                                                   const float* __restrict__ K,
                                                   const float* __restrict__ V,
                                                   bf16_t* __restrict__ X) {
    // LDS plan (bytes):
    //   Qslot : [0, 17408)       64*136 bf16   (Qh then Ql)   overlaid by Sf
    //   Kslot : [17408, 34816)   64*136 bf16   (Kh/Kl/Kh)     overlaid by Ps
    //   Vt    : [34816, 53248)   128*72 bf16
    //   Sf    : [0, 16640)       64*65  f32
    //   Ps    : [17408, 26624)   64*72  bf16
    __shared__ __align__(16) char smem[53248];
    bf16_t* Qs = (bf16_t*)smem;
    bf16_t* Ks = (bf16_t*)(smem + 17408);
    bf16_t* Vt = (bf16_t*)(smem + 34816);
    float*  Sf = (float*)smem;
    bf16_t* Ps = (bf16_t*)(smem + 17408);

    const int bh   = blockIdx.x;         // b*16 + h
    const int b    = bh >> 4;
    const int h    = bh & 15;
    const int t    = threadIdx.x;
    const int w    = t >> 6;             // wave 0..3
    const int lane = t & 63;
    const int row16 = lane & 15;
    const int quad  = lane >> 4;

    const float* Qg = Q + (size_t)bh * 8192;
    const float* Kg = K + (size_t)bh * 8192;
    const float* Vg = V + (size_t)bh * 8192;

    const int r  = t >> 2;            // 0..63
    const int c0 = (t & 3) * 32;      // 0,32,64,96

    // ---- load this thread's Q/K fp32 stripes into registers; stage Vt ----
    float qv[32], kv[32];
#pragma unroll
    for (int j = 0; j < 8; ++j) {
        const int c = c0 + 4 * j;
        *(float4*)&qv[4 * j] = *(const float4*)&Qg[r * 128 + c];
        *(float4*)&kv[4 * j] = *(const float4*)&Kg[r * 128 + c];
        const float4 v4 = *(const float4*)&Vg[r * 128 + c];
        Vt[(c + 0) * VT_LD + r] = (bf16_t)v4.x;
        Vt[(c + 1) * VT_LD + r] = (bf16_t)v4.y;
        Vt[(c + 2) * VT_LD + r] = (bf16_t)v4.z;
        Vt[(c + 3) * VT_LD + r] = (bf16_t)v4.w;
    }

    // stage helpers: write this thread's stripe into a slot
#define STAGE(slot, vals, CONV)                                            \
    {                                                                      \
        _Pragma("unroll")                                                  \
        for (int j = 0; j < 8; ++j) {                                      \
            const int c = c0 + 4 * j;                                      \
            bf16x4 o = { CONV(vals[4*j+0]), CONV(vals[4*j+1]),             \
                         CONV(vals[4*j+2]), CONV(vals[4*j+3]) };           \
            *(bf16x4*)&slot[r * QK_LD + c] = o;                            \
        }                                                                  \
    }

    f32x4 accS[4];
#pragma unroll
    for (int ni = 0; ni < 4; ++ni) accS[ni] = (f32x4){0.f, 0.f, 0.f, 0.f};

#define SCORE_PASS()                                                       \
    {                                                                      \
        _Pragma("unroll")                                                  \
        for (int kb = 0; kb < 4; ++kb) {                                   \
            const bf16x8 a = *(const bf16x8*)&Qs[(16*w + row16)*QK_LD + 32*kb + 8*quad]; \
            _Pragma("unroll")                                              \
            for (int ni = 0; ni < 4; ++ni) {                               \
                const bf16x8 bb = *(const bf16x8*)&Ks[(16*ni + row16)*QK_LD + 32*kb + 8*quad]; \
                accS[ni] = __builtin_amdgcn_mfma_f32_16x16x32_bf16(a, bb, accS[ni], 0, 0, 0); \
            }                                                              \
        }                                                                  \
    }

    // pass 1: Qh * Kh
    STAGE(Qs, qv, bhi)
    STAGE(Ks, kv, bhi)
    __syncthreads();
    SCORE_PASS()
    __syncthreads();
    // pass 2: Qh * Kl
    STAGE(Ks, kv, blo)
    __syncthreads();
    SCORE_PASS()
    __syncthreads();
    // pass 3: Ql * Kl
    STAGE(Qs, qv, blo)
    __syncthreads();
    SCORE_PASS()
    __syncthreads();
    // pass 4: Ql * Kh
    STAGE(Ks, kv, bhi)
    __syncthreads();
    SCORE_PASS()
    __syncthreads();   // all MFMA reads done before Sf overlays Qs

    // ---- spill S to LDS fp32 (C/D layout: col=lane&15, row=quad*4+reg)
#pragma unroll
    for (int ni = 0; ni < 4; ++ni)
#pragma unroll
        for (int rr = 0; rr < 4; ++rr)
            Sf[(16 * w + 4 * quad + rr) * SF_LD + 16 * ni + row16] = accS[ni][rr];
    __syncthreads();

    // ---- softmax rows; 4 lanes per row; write P bf16 (overlays Ks)
    {
        const int c16 = (t & 3) * 16;
        float x[16];
        float mx = -1e30f;
#pragma unroll
        for (int j = 0; j < 16; ++j) {
            x[j] = Sf[r * SF_LD + c16 + j] * 0.1f;
            mx = fmaxf(mx, x[j]);
        }
        mx = fmaxf(mx, __shfl_xor(mx, 1));
        mx = fmaxf(mx, __shfl_xor(mx, 2));
        float sum = 0.f;
#pragma unroll
        for (int j = 0; j < 16; ++j) {
            x[j] = exp2f((x[j] - mx) * 1.44269504088896f);
            sum += x[j];
        }
        sum += __shfl_xor(sum, 1);
        sum += __shfl_xor(sum, 2);
        const float inv = 1.0f / sum;
#pragma unroll
        for (int j4 = 0; j4 < 4; ++j4) {
            bf16x4 p = { (bf16_t)(x[4 * j4 + 0] * inv), (bf16_t)(x[4 * j4 + 1] * inv),
                         (bf16_t)(x[4 * j4 + 2] * inv), (bf16_t)(x[4 * j4 + 3] * inv) };
            *(bf16x4*)&Ps[r * VT_LD + c16 + 4 * j4] = p;
        }
    }
    __syncthreads();

    // ---- O[l,d] = sum_s P[l,s] V[s,d]; wave w rows 16w..16w+15, 8 d-tiles
    f32x4 accO[8];
#pragma unroll
    for (int ni = 0; ni < 8; ++ni) accO[ni] = (f32x4){0.f, 0.f, 0.f, 0.f};
#pragma unroll
    for (int kb = 0; kb < 2; ++kb) {
        const bf16x8 a = *(const bf16x8*)&Ps[(16 * w + row16) * VT_LD + 32 * kb + 8 * quad];
#pragma unroll
        for (int ni = 0; ni < 8; ++ni) {
            const bf16x8 bb = *(const bf16x8*)&Vt[(16 * ni + row16) * VT_LD + 32 * kb + 8 * quad];
            accO[ni] = __builtin_amdgcn_mfma_f32_16x16x32_bf16(a, bb, accO[ni], 0, 0, 0);
        }
    }

    // ---- epilogue: X[(b*64+l)][h*128+d]
    bf16_t* Xrow = X + (size_t)b * 64 * 2048 + h * 128;
#pragma unroll
    for (int ni = 0; ni < 8; ++ni)
#pragma unroll
        for (int rr = 0; rr < 4; ++rr) {
            const int l = 16 * w + 4 * quad + rr;
            const int d = 16 * ni + row16;
            Xrow[(size_t)l * 2048 + d] = (bf16_t)accO[ni][rr];
        }
}

// ---------------------------------------------------------------------------
// Kernel 3: out[m,n] = sum_k X[m,k] Wb[n,k] + bias[n]  (M=8192,N=2048,K=2048)
// m97 structure: 128x128 tile, BK=32, 256 thr, global_load_lds width 16.
// OUT IS FLOAT32 (reference output dtype).
// ---------------------------------------------------------------------------
__global__ __launch_bounds__(256) void gemm_kernel(const bf16_t* __restrict__ X,
                                                   const bf16_t* __restrict__ Wb,
                                                   const float* __restrict__ bias,
                                                   float* __restrict__ out) {
    __shared__ bf16_t As[128 * 32];   // [row][32], 64B rows (global_load_lds layout)
    __shared__ bf16_t Bs[128 * 32];

    const int t    = threadIdx.x;
    const int w    = t >> 6;
    const int lane = t & 63;
    const int row16 = lane & 15;
    const int quad  = lane >> 4;
    const int m0 = blockIdx.y * 128;
    const int n0 = blockIdx.x * 128;
    const int wm = w >> 1;            // 2x2 wave grid, each wave 64x64
    const int wn = w & 1;

    // staging: wave w stages rows [32w,32w+32); lane -> (row=lane>>2, col=(lane&3)*8)
    const int srow = 32 * w + (lane >> 2);
    const int scol = (lane & 3) * 8;
    const bf16_t* gA = X  + (size_t)(m0 + srow) * 2048 + scol;
    const bf16_t* gB = Wb + (size_t)(n0 + srow) * 2048 + scol;
    bf16_t* lA0 = &As[(32 * w) * 32];
    bf16_t* lA1 = &As[(32 * w + 16) * 32];
    bf16_t* lB0 = &Bs[(32 * w) * 32];
    bf16_t* lB1 = &Bs[(32 * w + 16) * 32];

    f32x4 acc[4][4];
#pragma unroll
    for (int mi = 0; mi < 4; ++mi)
#pragma unroll
        for (int ni = 0; ni < 4; ++ni) acc[mi][ni] = (f32x4){0.f, 0.f, 0.f, 0.f};

    for (int kb = 0; kb < 64; ++kb) {
        const int k0 = kb * 32;
        __syncthreads();                       // previous compute done before overwrite
        gld_lds16(gA + k0, lA0);
        gld_lds16(gA + 16 * 2048 + k0, lA1);
        gld_lds16(gB + k0, lB0);
        gld_lds16(gB + 16 * 2048 + k0, lB1);
        __syncthreads();                       // staged (compiler drains vmcnt)

        bf16x8 a[4], bb[4];
#pragma unroll
        for (int mi = 0; mi < 4; ++mi)
            a[mi] = *(const bf16x8*)&As[(64 * wm + 16 * mi + row16) * 32 + 8 * quad];
#pragma unroll
        for (int ni = 0; ni < 4; ++ni)
            bb[ni] = *(const bf16x8*)&Bs[(64 * wn + 16 * ni + row16) * 32 + 8 * quad];
#pragma unroll
        for (int mi = 0; mi < 4; ++mi)
#pragma unroll
            for (int ni = 0; ni < 4; ++ni)
                acc[mi][ni] = __builtin_amdgcn_mfma_f32_16x16x32_bf16(a[mi], bb[ni], acc[mi][ni], 0, 0, 0);
    }

    // epilogue: add bias, store FP32
    const int nb = n0 + 64 * wn;
    float br[4];
#pragma unroll
    for (int ni = 0; ni < 4; ++ni) br[ni] = bias[nb + 16 * ni + row16];
#pragma unroll
    for (int mi = 0; mi < 4; ++mi)
#pragma unroll
        for (int ni = 0; ni < 4; ++ni)
#pragma unroll
            for (int rr = 0; rr < 4; ++rr) {
                const int m = m0 + 64 * wm + 16 * mi + 4 * quad + rr;
                const int n = nb + 16 * ni + row16;
                out[(size_t)m * 2048 + n] = acc[mi][ni][rr] + br[ni];
            }
}

// ---------------------------------------------------------------------------
extern "C" void kernel_launch(void* const* d_in, const int* in_sizes, int n_in,
                              void* d_out, int out_size, void* d_ws, size_t ws_size,
                              hipStream_t stream) {
    // Inputs fp32 (reference dtypes); output fp32.
    const float* Q    = (const float*)d_in[0];
    const float* K    = (const float*)d_in[1];
    const float* V    = (const float*)d_in[2];
    const float* W    = (const float*)d_in[3];
    const float* bias = (const float*)d_in[4];

    bf16_t* Xws = (bf16_t*)d_ws;                                    // 32 MiB
    bf16_t* Wb  = (bf16_t*)((char*)d_ws + (size_t)8192 * 2048 * 2); // 8 MiB (ws>=40MiB per R1)
    float*  out = (float*)d_out;

    wconv_kernel<<<4096, 256, 0, stream>>>(W, Wb);
    attn_kernel<<<2048, 256, 0, stream>>>(Q, K, V, Xws);
    gemm_kernel<<<dim3(16, 64), 256, 0, stream>>>(Xws, Wb, bias, out);
}

// Round 4
// 298.574 us; speedup vs baseline: 1.0885x; 1.0885x over previous
//
#include <hip/hip_runtime.h>
#include <hip/hip_bf16.h>
#include <stdint.h>

typedef __bf16 bf16_t;
typedef __bf16 bf16x4 __attribute__((ext_vector_type(4)));
typedef __bf16 bf16x8 __attribute__((ext_vector_type(8)));
typedef float  f32x4  __attribute__((ext_vector_type(4)));

#define AS1 __attribute__((address_space(1)))
#define AS3 __attribute__((address_space(3)))

// async global->LDS, 16B per lane; lds dest = wave-uniform base + lane*16
__device__ __forceinline__ void gld_lds16(const void* gp, void* lp) {
    __builtin_amdgcn_global_load_lds((const AS1 unsigned int*)gp,
                                     (AS3 unsigned int*)lp, 16, 0, 0);
}

__device__ __forceinline__ bf16_t bhi(float v) { return (bf16_t)v; }
__device__ __forceinline__ bf16_t blo(float v) {
    return (bf16_t)(v - (float)((bf16_t)v));
}

// ---------------------------------------------------------------------------
// Kernel 1: W fp32 -> bf16
// ---------------------------------------------------------------------------
__global__ __launch_bounds__(256) void wconv_kernel(const float* __restrict__ W,
                                                    bf16_t* __restrict__ Wb) {
    const int i = (blockIdx.x * 256 + threadIdx.x) * 4;
    const float4 f = *(const float4*)&W[i];
    bf16x4 v = { (bf16_t)f.x, (bf16_t)f.y, (bf16_t)f.z, (bf16_t)f.w };
    *(bf16x4*)&Wb[i] = v;
}

// ---------------------------------------------------------------------------
// Kernel 2: attention per (b,h).  L=64, E=128.  fp32 in, bf16 X out.
// Scores via 3 Gray-code MFMA passes: Qh*Kl -> Qh*Kh -> Ql*Kh
// ((l,l) term ~2^-18 relative — negligible).  fp32 softmax, bf16 PV MFMA.
// X[(b*64+l)][h*128+d] bf16 (row stride 2048), coalesced via LDS roundtrip.
// ---------------------------------------------------------------------------
#define QK_LD 136   // 128 + 8 pad (keeps 16B align for ds_read_b128)
#define VT_LD 72    // 64 + 8 pad
#define SF_LD 65

__global__ __launch_bounds__(256) void attn_kernel(const float* __restrict__ Q,
                                                   const float* __restrict__ K,
                                                   const float* __restrict__ V,
                                                   bf16_t* __restrict__ X) {
    // LDS plan (bytes):
    //   Qslot : [0, 17408)       64*136 bf16  (Qh then Ql)  overlaid by Sf, Ob
    //   Kslot : [17408, 34816)   64*136 bf16  (Kl/Kh)       overlaid by Ps
    //   Vt    : [34816, 53248)   128*72 bf16
    //   Sf    : [0, 16640)       64*65  f32
    //   Ps    : [17408, 26624)   64*72  bf16
    //   Ob    : [0, 17408)       64*136 bf16  (output coalescing buffer)
    __shared__ __align__(16) char smem[53248];
    bf16_t* Qs = (bf16_t*)smem;
    bf16_t* Ks = (bf16_t*)(smem + 17408);
    bf16_t* Vt = (bf16_t*)(smem + 34816);
    float*  Sf = (float*)smem;
    bf16_t* Ps = (bf16_t*)(smem + 17408);
    bf16_t* Ob = (bf16_t*)smem;

    const int bh   = blockIdx.x;         // b*16 + h
    const int b    = bh >> 4;
    const int h    = bh & 15;
    const int t    = threadIdx.x;
    const int w    = t >> 6;             // wave 0..3
    const int lane = t & 63;
    const int row16 = lane & 15;
    const int quad  = lane >> 4;

    const float* Qg = Q + (size_t)bh * 8192;
    const float* Kg = K + (size_t)bh * 8192;
    const float* Vg = V + (size_t)bh * 8192;

    const int r  = t >> 2;            // 0..63
    const int c0 = (t & 3) * 32;      // 0,32,64,96

    // ---- load Q/K fp32 stripes into registers; stage Vt (transposed bf16) ----
    float qv[32], kv[32];
#pragma unroll
    for (int j = 0; j < 8; ++j) {
        const int c = c0 + 4 * j;
        *(float4*)&qv[4 * j] = *(const float4*)&Qg[r * 128 + c];
        *(float4*)&kv[4 * j] = *(const float4*)&Kg[r * 128 + c];
        const float4 v4 = *(const float4*)&Vg[r * 128 + c];
        Vt[(c + 0) * VT_LD + r] = (bf16_t)v4.x;
        Vt[(c + 1) * VT_LD + r] = (bf16_t)v4.y;
        Vt[(c + 2) * VT_LD + r] = (bf16_t)v4.z;
        Vt[(c + 3) * VT_LD + r] = (bf16_t)v4.w;
    }

#define STAGE(slot, vals, CONV)                                            \
    {                                                                      \
        _Pragma("unroll")                                                  \
        for (int j = 0; j < 8; ++j) {                                      \
            const int c = c0 + 4 * j;                                      \
            bf16x4 o = { CONV(vals[4*j+0]), CONV(vals[4*j+1]),             \
                         CONV(vals[4*j+2]), CONV(vals[4*j+3]) };           \
            *(bf16x4*)&slot[r * QK_LD + c] = o;                            \
        }                                                                  \
    }

    f32x4 accS[4];
#pragma unroll
    for (int ni = 0; ni < 4; ++ni) accS[ni] = (f32x4){0.f, 0.f, 0.f, 0.f};

#define SCORE_PASS()                                                       \
    {                                                                      \
        _Pragma("unroll")                                                  \
        for (int kb = 0; kb < 4; ++kb) {                                   \
            const bf16x8 a = *(const bf16x8*)&Qs[(16*w + row16)*QK_LD + 32*kb + 8*quad]; \
            _Pragma("unroll")                                              \
            for (int ni = 0; ni < 4; ++ni) {                               \
                const bf16x8 bb = *(const bf16x8*)&Ks[(16*ni + row16)*QK_LD + 32*kb + 8*quad]; \
                accS[ni] = __builtin_amdgcn_mfma_f32_16x16x32_bf16(a, bb, accS[ni], 0, 0, 0); \
            }                                                              \
        }                                                                  \
    }

    // pass 1: Qh * Kl
    STAGE(Qs, qv, bhi)
    STAGE(Ks, kv, blo)
    __syncthreads();
    SCORE_PASS()
    __syncthreads();
    // pass 2: Qh * Kh
    STAGE(Ks, kv, bhi)
    __syncthreads();
    SCORE_PASS()
    __syncthreads();
    // pass 3: Ql * Kh
    STAGE(Qs, qv, blo)
    __syncthreads();
    SCORE_PASS()
    __syncthreads();   // all MFMA reads done before Sf overlays Qs

    // ---- spill S to LDS fp32 (C/D layout: col=lane&15, row=quad*4+reg)
#pragma unroll
    for (int ni = 0; ni < 4; ++ni)
#pragma unroll
        for (int rr = 0; rr < 4; ++rr)
            Sf[(16 * w + 4 * quad + rr) * SF_LD + 16 * ni + row16] = accS[ni][rr];
    __syncthreads();

    // ---- softmax rows; 4 lanes per row; write P bf16 (overlays Ks)
    {
        const int c16 = (t & 3) * 16;
        float x[16];
        float mx = -1e30f;
#pragma unroll
        for (int j = 0; j < 16; ++j) {
            x[j] = Sf[r * SF_LD + c16 + j] * 0.1f;
            mx = fmaxf(mx, x[j]);
        }
        mx = fmaxf(mx, __shfl_xor(mx, 1));
        mx = fmaxf(mx, __shfl_xor(mx, 2));
        float sum = 0.f;
#pragma unroll
        for (int j = 0; j < 16; ++j) {
            x[j] = exp2f((x[j] - mx) * 1.44269504088896f);
            sum += x[j];
        }
        sum += __shfl_xor(sum, 1);
        sum += __shfl_xor(sum, 2);
        const float inv = 1.0f / sum;
#pragma unroll
        for (int j4 = 0; j4 < 4; ++j4) {
            bf16x4 p = { (bf16_t)(x[4 * j4 + 0] * inv), (bf16_t)(x[4 * j4 + 1] * inv),
                         (bf16_t)(x[4 * j4 + 2] * inv), (bf16_t)(x[4 * j4 + 3] * inv) };
            *(bf16x4*)&Ps[r * VT_LD + c16 + 4 * j4] = p;
        }
    }
    __syncthreads();

    // ---- O[l,d] = sum_s P[l,s] V[s,d]; wave w rows 16w..16w+15, 8 d-tiles
    f32x4 accO[8];
#pragma unroll
    for (int ni = 0; ni < 8; ++ni) accO[ni] = (f32x4){0.f, 0.f, 0.f, 0.f};
#pragma unroll
    for (int kb = 0; kb < 2; ++kb) {
        const bf16x8 a = *(const bf16x8*)&Ps[(16 * w + row16) * VT_LD + 32 * kb + 8 * quad];
#pragma unroll
        for (int ni = 0; ni < 8; ++ni) {
            const bf16x8 bb = *(const bf16x8*)&Vt[(16 * ni + row16) * VT_LD + 32 * kb + 8 * quad];
            accO[ni] = __builtin_amdgcn_mfma_f32_16x16x32_bf16(a, bb, accO[ni], 0, 0, 0);
        }
    }

    // ---- O -> LDS (Sf region is dead after the softmax barrier) ----
#pragma unroll
    for (int ni = 0; ni < 8; ++ni)
#pragma unroll
        for (int rr = 0; rr < 4; ++rr)
            Ob[(16 * w + 4 * quad + rr) * QK_LD + 16 * ni + row16] = (bf16_t)accO[ni][rr];
    __syncthreads();

    // ---- coalesced store: thread -> row r, 32 elems at c0 ----
    {
        bf16_t* Xrow = X + (size_t)b * 64 * 2048 + h * 128 + (size_t)r * 2048;
#pragma unroll
        for (int j = 0; j < 4; ++j) {
            *(bf16x8*)&Xrow[c0 + 8 * j] = *(const bf16x8*)&Ob[r * QK_LD + c0 + 8 * j];
        }
    }
}

// ---------------------------------------------------------------------------
// Kernel 3: out[m,n] = sum_k X[m,k] Wb[n,k] + bias[n]  (M=8192,N=2048,K=2048)
// 128x128 tile, BK=64, 256 thr, 4 blocks/CU, global_load_lds width 16.
// LDS tile [128 rows][8 chunks of 16B] with XOR swizzle p = q ^ (row&7):
// fragment reads hit all 32 banks evenly (conflict-free).
// Grid x = M-tiles so each XCD's X slice (4 MiB) stays L2-resident.
// ---------------------------------------------------------------------------
__global__ __launch_bounds__(256, 4) void gemm_kernel(const bf16_t* __restrict__ X,
                                                      const bf16_t* __restrict__ Wb,
                                                      const float* __restrict__ bias,
                                                      float* __restrict__ out) {
    __shared__ bf16_t As[128 * 64];   // 16 KiB
    __shared__ bf16_t Bs[128 * 64];   // 16 KiB

    const int t    = threadIdx.x;
    const int w    = t >> 6;
    const int lane = t & 63;
    const int row16 = lane & 15;
    const int quad  = lane >> 4;
    const int m0 = blockIdx.x * 128;   // x = M (XCD locality for X)
    const int n0 = blockIdx.y * 128;
    const int wm = w >> 1;             // 2x2 wave grid, each wave 64x64
    const int wn = w & 1;

    // staging: wave w stages rows [32w,32w+32) of each tile, 4 insts of 8 rows.
    // lane -> (row8 = lane>>3, q = lane&7); global col swizzled: 8*(q ^ row8)
    const int row8 = lane >> 3;
    const int scol = 8 * ((lane & 7) ^ (row8 & 7));
    const bf16_t* gA = X  + (size_t)(m0 + 32 * w + row8) * 2048 + scol;
    const bf16_t* gB = Wb + (size_t)(n0 + 32 * w + row8) * 2048 + scol;
    bf16_t* lA = &As[(32 * w) * 64];
    bf16_t* lB = &Bs[(32 * w) * 64];

    // fragment read offsets (elements), swizzled: row*64 + 8*((4*kk+quad)^(row&7))
    const int sw = row16 & 7;
    int aoff[4][2], boff[4][2];
#pragma unroll
    for (int mi = 0; mi < 4; ++mi)
#pragma unroll
        for (int kk = 0; kk < 2; ++kk) {
            const int ar = 64 * wm + 16 * mi + row16;
            const int br = 64 * wn + 16 * mi + row16;
            aoff[mi][kk] = ar * 64 + 8 * ((4 * kk + quad) ^ sw);
            boff[mi][kk] = br * 64 + 8 * ((4 * kk + quad) ^ sw);
        }

    f32x4 acc[4][4];
#pragma unroll
    for (int mi = 0; mi < 4; ++mi)
#pragma unroll
        for (int ni = 0; ni < 4; ++ni) acc[mi][ni] = (f32x4){0.f, 0.f, 0.f, 0.f};

    for (int kb = 0; kb < 32; ++kb) {
        const int k0 = kb * 64;
        __syncthreads();                       // previous compute done before overwrite
#pragma unroll
        for (int i = 0; i < 4; ++i) {
            gld_lds16(gA + (size_t)(8 * i) * 2048 + k0, lA + (8 * i) * 64);
            gld_lds16(gB + (size_t)(8 * i) * 2048 + k0, lB + (8 * i) * 64);
        }
        __syncthreads();                       // staged (compiler drains vmcnt)

#pragma unroll
        for (int kk = 0; kk < 2; ++kk) {
            bf16x8 a[4], bb[4];
#pragma unroll
            for (int mi = 0; mi < 4; ++mi) a[mi]  = *(const bf16x8*)&As[aoff[mi][kk]];
#pragma unroll
            for (int ni = 0; ni < 4; ++ni) bb[ni] = *(const bf16x8*)&Bs[boff[ni][kk]];
#pragma unroll
            for (int mi = 0; mi < 4; ++mi)
#pragma unroll
                for (int ni = 0; ni < 4; ++ni)
                    acc[mi][ni] = __builtin_amdgcn_mfma_f32_16x16x32_bf16(a[mi], bb[ni], acc[mi][ni], 0, 0, 0);
        }
    }

    // epilogue: add bias, store FP32
    const int nb = n0 + 64 * wn;
    float br[4];
#pragma unroll
    for (int ni = 0; ni < 4; ++ni) br[ni] = bias[nb + 16 * ni + row16];
#pragma unroll
    for (int mi = 0; mi < 4; ++mi)
#pragma unroll
        for (int ni = 0; ni < 4; ++ni)
#pragma unroll
            for (int rr = 0; rr < 4; ++rr) {
                const int m = m0 + 64 * wm + 16 * mi + 4 * quad + rr;
                const int n = nb + 16 * ni + row16;
                out[(size_t)m * 2048 + n] = acc[mi][ni][rr] + br[ni];
            }
}

// ---------------------------------------------------------------------------
extern "C" void kernel_launch(void* const* d_in, const int* in_sizes, int n_in,
                              void* d_out, int out_size, void* d_ws, size_t ws_size,
                              hipStream_t stream) {
    const float* Q    = (const float*)d_in[0];
    const float* K    = (const float*)d_in[1];
    const float* V    = (const float*)d_in[2];
    const float* W    = (const float*)d_in[3];
    const float* bias = (const float*)d_in[4];

    bf16_t* Xws = (bf16_t*)d_ws;                                    // 32 MiB
    bf16_t* Wb  = (bf16_t*)((char*)d_ws + (size_t)8192 * 2048 * 2); // 8 MiB
    float*  out = (float*)d_out;

    wconv_kernel<<<4096, 256, 0, stream>>>(W, Wb);
    attn_kernel<<<2048, 256, 0, stream>>>(Q, K, V, Xws);
    gemm_kernel<<<dim3(64, 16), 256, 0, stream>>>(Xws, Wb, bias, out);
}